// Round 13
// baseline (211.620 us; speedup 1.0000x reference)
//
#include <hip/hip_runtime.h>
#include <stdint.h>

// GNN block: GCNConv(x@W, sym-norm agg w/ self loops) -> ReLU -> BatchNorm(train) -> JAX dropout
// R13: channel-chunked h + XCD-affine k_agg. h stored as 4 chunks of 32 channels (3.2MB each,
//      chunk-major). k_agg block = 4 nodes x 1 chunk, chunk derived from blockIdx%8 (XCD
//      round-robin) -> each XCD's gather working set is ONE chunk, L2-resident (3.2MB < 4MB).
//      Wave: 4 edge-groups x 16 lanes (64B line per edge), shfl_xor combine.
//      Mechanism check: k_agg FETCH 84MB -> <20MB if bid%8==XCD holds.
//      Everything else byte-identical to R12.

#define NN 50000
#define NE 800000
#define DD 128
#define SCAN_B 256
#define NSB ((NN + SCAN_B - 1) / SCAN_B)   // 196
#define NSTAT 400                          // k_stats blocks

using f32x4  = __attribute__((ext_vector_type(4))) float;
using short8 = __attribute__((ext_vector_type(8))) short;

// ---------------- threefry2x32 (JAX-compatible, partitionable path) ----------------
__device__ __forceinline__ uint32_t rotl32(uint32_t x, uint32_t d) {
  return (x << d) | (x >> (32u - d));
}

__device__ __forceinline__ uint32_t threefry_bits(uint32_t idx) {
  const uint32_t ks0 = 0u;
  const uint32_t ks1 = 42u;
  const uint32_t ks2 = 0x1BD11BDAu ^ ks0 ^ ks1;
  uint32_t x0 = ks0;
  uint32_t x1 = idx + ks1;
#define TF_R(r) { x0 += x1; x1 = rotl32(x1, (r)); x1 ^= x0; }
  TF_R(13u) TF_R(15u) TF_R(26u) TF_R(6u)
  x0 += ks1; x1 += ks2 + 1u;
  TF_R(17u) TF_R(29u) TF_R(16u) TF_R(24u)
  x0 += ks2; x1 += ks0 + 2u;
  TF_R(13u) TF_R(15u) TF_R(26u) TF_R(6u)
  x0 += ks0; x1 += ks1 + 3u;
  TF_R(17u) TF_R(29u) TF_R(16u) TF_R(24u)
  x0 += ks1; x1 += ks2 + 4u;
  TF_R(13u) TF_R(15u) TF_R(26u) TF_R(6u)
  x0 += ks2; x1 += ks0 + 5u;
#undef TF_R
  return x0 ^ x1;
}

__device__ __forceinline__ uint32_t f2bf(float f) {
  uint32_t u = __float_as_uint(f);
  return (u + 0x7fffu + ((u >> 16) & 1u)) >> 16;   // RNE
}
__device__ __forceinline__ float bf2f(uint32_t h) { return __uint_as_float(h << 16); }
__device__ __forceinline__ float bf_lo(uint32_t p) { return __uint_as_float(p << 16); }
__device__ __forceinline__ float bf_hi(uint32_t p) { return __uint_as_float(p & 0xffff0000u); }

// ---------------- W pre-pack into MFMA fragment order ----------------
__global__ __launch_bounds__(256) void k_wpack(const float* __restrict__ Wm,
                                               short8* __restrict__ wfh,
                                               short8* __restrict__ wfl) {
  int tid = blockIdx.x * 256 + threadIdx.x;   // 0..2047
  if (tid >= 32 * 64) return;
  int lane = tid & 63;
  int cfks = tid >> 6;        // ks = cfks>>3, cf = cfks&7
  int ks = cfks >> 3, cf = cfks & 7;
  int krow = ks * 32 + ((lane >> 4) << 3);
  int col = cf * 16 + (lane & 15);
  short8 h, l;
#pragma unroll
  for (int j = 0; j < 8; ++j) {
    float w = Wm[(size_t)(krow + j) * DD + col];
    uint32_t hb = f2bf(w);
    uint32_t lb = f2bf(w - bf2f(hb));
    h[j] = (short)hb;
    l[j] = (short)lb;
  }
  wfh[tid] = h;
  wfl[tid] = l;
}

// ---------------- MFMA GEMM: hc[chunk][N][32ch](bf16) = (x @ W) * dinv[row] ----------------
// chunk-major: chunk c holds channels [32c, 32c+32); uint2 layout: hc2[c*NN*8 + node*8 + w]
#define GBM 128
__global__ __launch_bounds__(256) void k_gemm(const float* __restrict__ x,
                                              const short8* __restrict__ wfh,
                                              const short8* __restrict__ wfl,
                                              const float* __restrict__ dinv,
                                              uint2* __restrict__ hc2) {
  __shared__ uint4 ldsbuf[4096];              // 64 KiB: xhi @0, xlo @32768
  char* lds = (char*)ldsbuf;
  const int t = threadIdx.x;
  const int row0 = blockIdx.x * GBM;
  const int c4 = t & 31, rbase = t >> 5;

#pragma unroll
  for (int i = 0; i < 16; ++i) {
    int r = rbase + i * 8;
    int grow = row0 + r;
    float4 v = make_float4(0.f, 0.f, 0.f, 0.f);
    if (grow < NN)
      v = *reinterpret_cast<const float4*>(&x[(size_t)grow * DD + c4 * 4]);
    uint32_t h0 = f2bf(v.x), h1 = f2bf(v.y), h2 = f2bf(v.z), h3 = f2bf(v.w);
    uint32_t l0 = f2bf(v.x - bf2f(h0)), l1 = f2bf(v.y - bf2f(h1));
    uint32_t l2 = f2bf(v.z - bf2f(h2)), l3 = f2bf(v.w - bf2f(h3));
    int byte = (r * 256 + c4 * 8) ^ ((r & 7) << 4);
    *reinterpret_cast<uint2*>(lds + byte) = make_uint2(h0 | (h1 << 16), h2 | (h3 << 16));
    *reinterpret_cast<uint2*>(lds + 32768 + byte) = make_uint2(l0 | (l1 << 16), l2 | (l3 << 16));
  }
  __syncthreads();

  const int wv = t >> 6, l = t & 63;
  f32x4 acc[2][8] = {};
#pragma unroll
  for (int ks = 0; ks < 4; ++ks) {
    short8 ah[2], al[2];
#pragma unroll
    for (int rf = 0; rf < 2; ++rf) {
      int r = wv * 32 + rf * 16 + (l & 15);
      int byte = (r * 256 + ks * 64 + ((l >> 4) << 4)) ^ ((r & 7) << 4);
      ah[rf] = *reinterpret_cast<const short8*>(lds + byte);
      al[rf] = *reinterpret_cast<const short8*>(lds + 32768 + byte);
    }
#pragma unroll
    for (int cf = 0; cf < 8; ++cf) {
      short8 bh = wfh[(ks * 8 + cf) * 64 + l];
      short8 bl = wfl[(ks * 8 + cf) * 64 + l];
#pragma unroll
      for (int rf = 0; rf < 2; ++rf) {
        acc[rf][cf] = __builtin_amdgcn_mfma_f32_16x16x32_bf16(ah[rf], bl, acc[rf][cf], 0, 0, 0);
        acc[rf][cf] = __builtin_amdgcn_mfma_f32_16x16x32_bf16(al[rf], bh, acc[rf][cf], 0, 0, 0);
        acc[rf][cf] = __builtin_amdgcn_mfma_f32_16x16x32_bf16(ah[rf], bh, acc[rf][cf], 0, 0, 0);
      }
    }
  }
  __syncthreads();   // reuse LDS for output repack

#pragma unroll
  for (int rf = 0; rf < 2; ++rf)
#pragma unroll
    for (int i = 0; i < 4; ++i) {
      int row = wv * 32 + rf * 16 + ((l >> 4) << 2) + i;
      int grow = row0 + row;
      float dv = (grow < NN) ? dinv[grow] : 0.f;
#pragma unroll
      for (int cf = 0; cf < 8; ++cf) {
        int col = cf * 16 + (l & 15);
        int byte = (row * 256 + col * 2) ^ ((row & 7) << 4);
        *reinterpret_cast<uint16_t*>(lds + byte) = (uint16_t)f2bf(acc[rf][cf][i] * dv);
      }
    }
  __syncthreads();
#pragma unroll
  for (int i = 0; i < 16; ++i) {
    int r = rbase + i * 8;
    int grow = row0 + r;
    if (grow < NN) {
      int byte = (r * 256 + c4 * 8) ^ ((r & 7) << 4);
      uint2 v = *reinterpret_cast<const uint2*>(lds + byte);
      // chunked store: c4 covers channels [c4*4, c4*4+4) -> chunk = c4>>3, slot = c4&7
      hc2[(size_t)(c4 >> 3) * NN * 8 + (size_t)grow * 8 + (c4 & 7)] = v;
    }
  }
}

// ---------------- degree count + slot assignment: 2 edges/thread, packed u16 pos ----------------
__global__ void k_count(const int* __restrict__ ei, int* __restrict__ cnt,
                        uint32_t* __restrict__ pos2) {
  int e2 = blockIdx.x * blockDim.x + threadIdx.x;
  int e = e2 * 2;
  if (e < NE) {
    int2 d = *reinterpret_cast<const int2*>(&ei[NE + e]);
    uint32_t p0 = (uint32_t)atomicAdd(&cnt[d.x], 1) & 0xffffu;
    uint32_t p1 = (uint32_t)atomicAdd(&cnt[d.y], 1) & 0xffffu;
    pos2[e2] = p0 | (p1 << 16);
  }
}

// ---------------- scan stage 1: block-inclusive scan + dinv ----------------
__global__ __launch_bounds__(SCAN_B) void k_scan1(const int* __restrict__ cnt,
                                                  int* __restrict__ tmp,
                                                  int* __restrict__ blk_sums,
                                                  float* __restrict__ dinv) {
  __shared__ int sm[SCAN_B];
  int t = threadIdx.x;
  int i = blockIdx.x * SCAN_B + t;
  int v = (i < NN) ? cnt[i] : 0;
  if (i < NN) dinv[i] = rsqrtf((float)v + 1.0f);
  sm[t] = v;
  __syncthreads();
  for (int off = 1; off < SCAN_B; off <<= 1) {
    int u = (t >= off) ? sm[t - off] : 0;
    __syncthreads();
    sm[t] += u;
    __syncthreads();
  }
  if (i < NN) tmp[i] = sm[t];
  if (t == SCAN_B - 1) blk_sums[blockIdx.x] = sm[t];
}

// ---------------- scan stage 3: row_ptr (block-offset recomputed locally) ----------------
__global__ __launch_bounds__(SCAN_B) void k_scan3(const int* __restrict__ tmp,
                                                  const int* __restrict__ blk_sums,
                                                  int* __restrict__ row_ptr) {
  __shared__ int sm[SCAN_B];
  int t = threadIdx.x;
  int v = (t < NSB) ? blk_sums[t] : 0;
  sm[t] = v;
  __syncthreads();
  for (int off = 1; off < SCAN_B; off <<= 1) {
    int u = (t >= off) ? sm[t - off] : 0;
    __syncthreads();
    sm[t] += u;
    __syncthreads();
  }
  int excl = sm[blockIdx.x] - blk_sums[blockIdx.x];
  int i = blockIdx.x * SCAN_B + t;
  if (i < NN) {
    row_ptr[i + 1] = tmp[i] + excl;
    if (i == 0) row_ptr[0] = 0;
  }
}

// ---------------- CSR fill: 2 edges/thread, atomic-free, u16 colv ----------------
__global__ void k_fill(const int* __restrict__ ei, const int* __restrict__ row_ptr,
                       const uint32_t* __restrict__ pos2, uint16_t* __restrict__ colv) {
  int e2 = blockIdx.x * blockDim.x + threadIdx.x;
  int e = e2 * 2;
  if (e < NE) {
    int2 s = *reinterpret_cast<const int2*>(&ei[e]);
    int2 d = *reinterpret_cast<const int2*>(&ei[NE + e]);
    uint32_t pp = pos2[e2];
    colv[row_ptr[d.x] + (int)(pp & 0xffffu)] = (uint16_t)s.x;
    colv[row_ptr[d.y] + (int)(pp >> 16)]     = (uint16_t)s.y;
  }
}

// ---------------- aggregate: XCD-affine channel-chunked gather ----------------
// block = 4 nodes x 1 chunk; chunk = (bid&7)>>1 so each XCD touches one 3.2MB chunk.
// wave: 4 edge-groups (eg=lane>>4) x 16 lanes (2ch each); 64B line per edge; shfl combine.
__global__ __launch_bounds__(256) void k_agg(const uint32_t* __restrict__ hc,
                                             const int* __restrict__ row_ptr,
                                             const uint16_t* __restrict__ colv,
                                             const float* __restrict__ dinv,
                                             const float* __restrict__ bias,
                                             float* __restrict__ z) {
  int bid = blockIdx.x;
  int wave = threadIdx.x >> 6;
  int lane = threadIdx.x & 63;
  int sub = bid & 7;
  int chunk = sub >> 1;
  int ng = (bid >> 3) * 2 + (sub & 1);     // 0..12499
  int node = ng * 4 + wave;                // < 50000
  int eg = lane >> 4;                      // edge group 0..3
  int ch2 = lane & 15;                     // 2 channels: chunk*32 + ch2*2

  const uint32_t* hcc = hc + (size_t)chunk * NN * 16;
  float ax = 0.f, ay = 0.f;
  int beg = row_ptr[node], end = row_ptr[node + 1];
  for (int base = beg; base < end; base += 4) {
    int ee = base + eg;
    bool ok = ee < end;
    int s = colv[ok ? ee : beg];
    uint32_t m = hcc[(size_t)s * 16 + ch2];
    m = ok ? m : 0u;
    ax += bf_lo(m);
    ay += bf_hi(m);
  }
  ax += __shfl_xor(ax, 16); ay += __shfl_xor(ay, 16);
  ax += __shfl_xor(ax, 32); ay += __shfl_xor(ay, 32);
  if (lane < 16) {
    uint32_t ms = hcc[(size_t)node * 16 + ch2];    // self-loop (pre-scaled)
    ax += bf_lo(ms);
    ay += bf_hi(ms);
    float di = dinv[node];
    int col = chunk * 32 + ch2 * 2;
    float2 bb = *reinterpret_cast<const float2*>(&bias[col]);
    float zx = fmaxf(fmaf(ax, di, bb.x), 0.f);
    float zy = fmaxf(fmaf(ay, di, bb.y), 0.f);
    *reinterpret_cast<float2*>(&z[(size_t)node * DD + col]) = make_float2(zx, zy);
  }
}

// ---------------- BN stats stage 1: per-block partials, NO atomics ----------------
__global__ __launch_bounds__(256) void k_stats(const float* __restrict__ z,
                                               float* __restrict__ part) {
  int t = threadIdx.x;
  int c4 = t & 31;
  int rgrp = t >> 5;
  float sx = 0.f, sy = 0.f, sz = 0.f, sw = 0.f;
  float qx = 0.f, qy = 0.f, qz = 0.f, qw = 0.f;
  for (int r = blockIdx.x * 8 + rgrp; r < NN; r += NSTAT * 8) {
    float4 v = *reinterpret_cast<const float4*>(&z[(size_t)r * DD + c4 * 4]);
    sx += v.x; sy += v.y; sz += v.z; sw += v.w;
    qx = fmaf(v.x, v.x, qx); qy = fmaf(v.y, v.y, qy);
    qz = fmaf(v.z, v.z, qz); qw = fmaf(v.w, v.w, qw);
  }
  __shared__ float sm[2048], sm2[2048];
  sm[t * 4 + 0] = sx; sm[t * 4 + 1] = sy; sm[t * 4 + 2] = sz; sm[t * 4 + 3] = sw;
  sm2[t * 4 + 0] = qx; sm2[t * 4 + 1] = qy; sm2[t * 4 + 2] = qz; sm2[t * 4 + 3] = qw;
  __syncthreads();
  int c = t & 127;
  float acc = 0.f;
  if (t < 128) {
#pragma unroll
    for (int g = 0; g < 8; ++g) acc += sm[g * 128 + c];
  } else {
#pragma unroll
    for (int g = 0; g < 8; ++g) acc += sm2[g * 128 + c];
  }
  part[blockIdx.x * 256 + t] = acc;
}

// ---------------- BN stats stage 2: reduce partials (1 block) ----------------
__global__ __launch_bounds__(256) void k_stats2(const float* __restrict__ part,
                                                float* __restrict__ bn_sum,
                                                float* __restrict__ bn_sumsq) {
  int t = threadIdx.x;
  float acc = 0.f;
  for (int b = 0; b < NSTAT; ++b) acc += part[b * 256 + t];
  if (t < 128) bn_sum[t] = acc;
  else bn_sumsq[t - 128] = acc;
}

// ---------------- finalize: BN + dropout (float4 per thread, full grid) ----------------
__global__ __launch_bounds__(256) void k_final(float* __restrict__ z,
                                               const float* __restrict__ bn_sum,
                                               const float* __restrict__ bn_sumsq,
                                               const float* __restrict__ gamma,
                                               const float* __restrict__ beta) {
  int j4 = blockIdx.x * blockDim.x + threadIdx.x;
  if (j4 >= NN * DD / 4) return;
  int c4 = j4 & 31;
  const float invN = 1.0f / (float)NN;
  float4 s = *reinterpret_cast<const float4*>(&bn_sum[c4 * 4]);
  float4 q = *reinterpret_cast<const float4*>(&bn_sumsq[c4 * 4]);
  float4 g = *reinterpret_cast<const float4*>(&gamma[c4 * 4]);
  float4 bt = *reinterpret_cast<const float4*>(&beta[c4 * 4]);
  float4 v = *reinterpret_cast<const float4*>(&z[(size_t)j4 * 4]);
  float out[4];
  float mm[4] = {s.x * invN, s.y * invN, s.z * invN, s.w * invN};
  float qq[4] = {q.x * invN, q.y * invN, q.z * invN, q.w * invN};
  float gg[4] = {g.x, g.y, g.z, g.w};
  float bb[4] = {bt.x, bt.y, bt.z, bt.w};
  float vv[4] = {v.x, v.y, v.z, v.w};
#pragma unroll
  for (int i = 0; i < 4; ++i) {
    float var = qq[i] - mm[i] * mm[i];
    float rs = rsqrtf(var + 1e-5f);
    float val = (vv[i] - mm[i]) * rs * gg[i] + bb[i];
    uint32_t bits = threefry_bits((uint32_t)(j4 * 4 + i));
    float u = __uint_as_float((bits >> 9) | 0x3f800000u) - 1.0f;
    out[i] = (u < 0.9f) ? val * (1.0f / 0.9f) : 0.0f;
  }
  *reinterpret_cast<float4*>(&z[(size_t)j4 * 4]) = make_float4(out[0], out[1], out[2], out[3]);
}

// ---------------- launch ----------------
extern "C" void kernel_launch(void* const* d_in, const int* in_sizes, int n_in,
                              void* d_out, int out_size, void* d_ws, size_t ws_size,
                              hipStream_t stream) {
  const float* x     = (const float*)d_in[0];
  const int*   ei    = (const int*)d_in[1];
  const float* Wm    = (const float*)d_in[2];
  const float* bvec  = (const float*)d_in[3];
  const float* gamma = (const float*)d_in[4];
  const float* beta  = (const float*)d_in[5];
  float* zout = (float*)d_out;

  // workspace layout
  uint32_t* hc   = (uint32_t*)d_ws;                         // 4 chunks x NN x 64B (12.8MB)
  short8* wfh    = (short8*)(hc + (size_t)NN * 16 * 4 / 4 * 4);  // == hc + NN*64 words
  wfh            = (short8*)((uint16_t*)d_ws + (size_t)NN * DD); // NN*DD bf16 total
  short8* wfl    = wfh + 2048;                              // 32KB
  uint16_t* colv = (uint16_t*)(wfl + 2048);                 // NE u16
  uint32_t* pos2 = (uint32_t*)(colv + NE);                  // NE/2 u32 (packed u16 pairs)
  int* cnt       = (int*)(pos2 + NE / 2);                   // NN (zeroed)
  float* bn_sum  = (float*)(cnt + NN);                      // DD
  float* bn_sumsq= bn_sum + DD;                             // DD
  int* tmp_scan  = (int*)(bn_sumsq + DD);                   // NN
  int* row_ptr   = tmp_scan + NN;                           // NN+1
  float* dinv    = (float*)(row_ptr + NN + 1);              // NN
  int* blk_sums  = (int*)(dinv + NN);                       // NSB
  float* part    = (float*)(blk_sums + NSB);                // NSTAT*256

  hipMemsetAsync(cnt, 0, (size_t)NN * sizeof(int), stream);

  k_wpack<<<8, 256, 0, stream>>>(Wm, wfh, wfl);
  k_count<<<(NE / 2 + 255) / 256, 256, 0, stream>>>(ei, cnt, pos2);
  k_scan1<<<NSB, SCAN_B, 0, stream>>>(cnt, tmp_scan, blk_sums, dinv);
  k_scan3<<<NSB, SCAN_B, 0, stream>>>(tmp_scan, blk_sums, row_ptr);
  k_gemm<<<(NN + GBM - 1) / GBM, 256, 0, stream>>>(x, wfh, wfl, dinv, (uint2*)hc);
  k_fill<<<(NE / 2 + 255) / 256, 256, 0, stream>>>(ei, row_ptr, pos2, colv);
  k_agg<<<12500 * 4, 256, 0, stream>>>(hc, row_ptr, colv, dinv, bvec, zout);
  k_stats<<<NSTAT, 256, 0, stream>>>(zout, part);
  k_stats2<<<1, 256, 0, stream>>>(part, bn_sum, bn_sumsq);
  k_final<<<(NN * DD / 4 + 255) / 256, 256, 0, stream>>>(zout, bn_sum, bn_sumsq, gamma, beta);
}

// Round 14
// 179.035 us; speedup vs baseline: 1.1820x; 1.1820x over previous
//
#include <hip/hip_runtime.h>
#include <stdint.h>

// GNN block: GCNConv(x@W, sym-norm agg w/ self loops) -> ReLU -> BatchNorm(train) -> JAX dropout
// R14: chunked k_agg with batching restored. R13 proved the XCD-affine chunk mechanism
//      (FETCH 84->27MB) but lost MLP (serial 4-edge steps, 93us). Now: unmasked 16-edge
//      batches (4 loads in flight/lane) + ONE masked 4-slot tail batch (tail<16 edges).
//      Everything else identical to R13.

#define NN 50000
#define NE 800000
#define DD 128
#define SCAN_B 256
#define NSB ((NN + SCAN_B - 1) / SCAN_B)   // 196
#define NSTAT 400                          // k_stats blocks

using f32x4  = __attribute__((ext_vector_type(4))) float;
using short8 = __attribute__((ext_vector_type(8))) short;

// ---------------- threefry2x32 (JAX-compatible, partitionable path) ----------------
__device__ __forceinline__ uint32_t rotl32(uint32_t x, uint32_t d) {
  return (x << d) | (x >> (32u - d));
}

__device__ __forceinline__ uint32_t threefry_bits(uint32_t idx) {
  const uint32_t ks0 = 0u;
  const uint32_t ks1 = 42u;
  const uint32_t ks2 = 0x1BD11BDAu ^ ks0 ^ ks1;
  uint32_t x0 = ks0;
  uint32_t x1 = idx + ks1;
#define TF_R(r) { x0 += x1; x1 = rotl32(x1, (r)); x1 ^= x0; }
  TF_R(13u) TF_R(15u) TF_R(26u) TF_R(6u)
  x0 += ks1; x1 += ks2 + 1u;
  TF_R(17u) TF_R(29u) TF_R(16u) TF_R(24u)
  x0 += ks2; x1 += ks0 + 2u;
  TF_R(13u) TF_R(15u) TF_R(26u) TF_R(6u)
  x0 += ks0; x1 += ks1 + 3u;
  TF_R(17u) TF_R(29u) TF_R(16u) TF_R(24u)
  x0 += ks1; x1 += ks2 + 4u;
  TF_R(13u) TF_R(15u) TF_R(26u) TF_R(6u)
  x0 += ks2; x1 += ks0 + 5u;
#undef TF_R
  return x0 ^ x1;
}

__device__ __forceinline__ uint32_t f2bf(float f) {
  uint32_t u = __float_as_uint(f);
  return (u + 0x7fffu + ((u >> 16) & 1u)) >> 16;   // RNE
}
__device__ __forceinline__ float bf2f(uint32_t h) { return __uint_as_float(h << 16); }
__device__ __forceinline__ float bf_lo(uint32_t p) { return __uint_as_float(p << 16); }
__device__ __forceinline__ float bf_hi(uint32_t p) { return __uint_as_float(p & 0xffff0000u); }

// ---------------- W pre-pack into MFMA fragment order ----------------
__global__ __launch_bounds__(256) void k_wpack(const float* __restrict__ Wm,
                                               short8* __restrict__ wfh,
                                               short8* __restrict__ wfl) {
  int tid = blockIdx.x * 256 + threadIdx.x;   // 0..2047
  if (tid >= 32 * 64) return;
  int lane = tid & 63;
  int cfks = tid >> 6;        // ks = cfks>>3, cf = cfks&7
  int ks = cfks >> 3, cf = cfks & 7;
  int krow = ks * 32 + ((lane >> 4) << 3);
  int col = cf * 16 + (lane & 15);
  short8 h, l;
#pragma unroll
  for (int j = 0; j < 8; ++j) {
    float w = Wm[(size_t)(krow + j) * DD + col];
    uint32_t hb = f2bf(w);
    uint32_t lb = f2bf(w - bf2f(hb));
    h[j] = (short)hb;
    l[j] = (short)lb;
  }
  wfh[tid] = h;
  wfl[tid] = l;
}

// ---------------- MFMA GEMM: hc[chunk][N][32ch](bf16) = (x @ W) * dinv[row] ----------------
#define GBM 128
__global__ __launch_bounds__(256) void k_gemm(const float* __restrict__ x,
                                              const short8* __restrict__ wfh,
                                              const short8* __restrict__ wfl,
                                              const float* __restrict__ dinv,
                                              uint2* __restrict__ hc2) {
  __shared__ uint4 ldsbuf[4096];              // 64 KiB: xhi @0, xlo @32768
  char* lds = (char*)ldsbuf;
  const int t = threadIdx.x;
  const int row0 = blockIdx.x * GBM;
  const int c4 = t & 31, rbase = t >> 5;

#pragma unroll
  for (int i = 0; i < 16; ++i) {
    int r = rbase + i * 8;
    int grow = row0 + r;
    float4 v = make_float4(0.f, 0.f, 0.f, 0.f);
    if (grow < NN)
      v = *reinterpret_cast<const float4*>(&x[(size_t)grow * DD + c4 * 4]);
    uint32_t h0 = f2bf(v.x), h1 = f2bf(v.y), h2 = f2bf(v.z), h3 = f2bf(v.w);
    uint32_t l0 = f2bf(v.x - bf2f(h0)), l1 = f2bf(v.y - bf2f(h1));
    uint32_t l2 = f2bf(v.z - bf2f(h2)), l3 = f2bf(v.w - bf2f(h3));
    int byte = (r * 256 + c4 * 8) ^ ((r & 7) << 4);
    *reinterpret_cast<uint2*>(lds + byte) = make_uint2(h0 | (h1 << 16), h2 | (h3 << 16));
    *reinterpret_cast<uint2*>(lds + 32768 + byte) = make_uint2(l0 | (l1 << 16), l2 | (l3 << 16));
  }
  __syncthreads();

  const int wv = t >> 6, l = t & 63;
  f32x4 acc[2][8] = {};
#pragma unroll
  for (int ks = 0; ks < 4; ++ks) {
    short8 ah[2], al[2];
#pragma unroll
    for (int rf = 0; rf < 2; ++rf) {
      int r = wv * 32 + rf * 16 + (l & 15);
      int byte = (r * 256 + ks * 64 + ((l >> 4) << 4)) ^ ((r & 7) << 4);
      ah[rf] = *reinterpret_cast<const short8*>(lds + byte);
      al[rf] = *reinterpret_cast<const short8*>(lds + 32768 + byte);
    }
#pragma unroll
    for (int cf = 0; cf < 8; ++cf) {
      short8 bh = wfh[(ks * 8 + cf) * 64 + l];
      short8 bl = wfl[(ks * 8 + cf) * 64 + l];
#pragma unroll
      for (int rf = 0; rf < 2; ++rf) {
        acc[rf][cf] = __builtin_amdgcn_mfma_f32_16x16x32_bf16(ah[rf], bl, acc[rf][cf], 0, 0, 0);
        acc[rf][cf] = __builtin_amdgcn_mfma_f32_16x16x32_bf16(al[rf], bh, acc[rf][cf], 0, 0, 0);
        acc[rf][cf] = __builtin_amdgcn_mfma_f32_16x16x32_bf16(ah[rf], bh, acc[rf][cf], 0, 0, 0);
      }
    }
  }
  __syncthreads();   // reuse LDS for output repack

#pragma unroll
  for (int rf = 0; rf < 2; ++rf)
#pragma unroll
    for (int i = 0; i < 4; ++i) {
      int row = wv * 32 + rf * 16 + ((l >> 4) << 2) + i;
      int grow = row0 + row;
      float dv = (grow < NN) ? dinv[grow] : 0.f;
#pragma unroll
      for (int cf = 0; cf < 8; ++cf) {
        int col = cf * 16 + (l & 15);
        int byte = (row * 256 + col * 2) ^ ((row & 7) << 4);
        *reinterpret_cast<uint16_t*>(lds + byte) = (uint16_t)f2bf(acc[rf][cf][i] * dv);
      }
    }
  __syncthreads();
#pragma unroll
  for (int i = 0; i < 16; ++i) {
    int r = rbase + i * 8;
    int grow = row0 + r;
    if (grow < NN) {
      int byte = (r * 256 + c4 * 8) ^ ((r & 7) << 4);
      uint2 v = *reinterpret_cast<const uint2*>(lds + byte);
      hc2[(size_t)(c4 >> 3) * NN * 8 + (size_t)grow * 8 + (c4 & 7)] = v;
    }
  }
}

// ---------------- degree count + slot assignment: 2 edges/thread, packed u16 pos ----------------
__global__ void k_count(const int* __restrict__ ei, int* __restrict__ cnt,
                        uint32_t* __restrict__ pos2) {
  int e2 = blockIdx.x * blockDim.x + threadIdx.x;
  int e = e2 * 2;
  if (e < NE) {
    int2 d = *reinterpret_cast<const int2*>(&ei[NE + e]);
    uint32_t p0 = (uint32_t)atomicAdd(&cnt[d.x], 1) & 0xffffu;
    uint32_t p1 = (uint32_t)atomicAdd(&cnt[d.y], 1) & 0xffffu;
    pos2[e2] = p0 | (p1 << 16);
  }
}

// ---------------- scan stage 1: block-inclusive scan + dinv ----------------
__global__ __launch_bounds__(SCAN_B) void k_scan1(const int* __restrict__ cnt,
                                                  int* __restrict__ tmp,
                                                  int* __restrict__ blk_sums,
                                                  float* __restrict__ dinv) {
  __shared__ int sm[SCAN_B];
  int t = threadIdx.x;
  int i = blockIdx.x * SCAN_B + t;
  int v = (i < NN) ? cnt[i] : 0;
  if (i < NN) dinv[i] = rsqrtf((float)v + 1.0f);
  sm[t] = v;
  __syncthreads();
  for (int off = 1; off < SCAN_B; off <<= 1) {
    int u = (t >= off) ? sm[t - off] : 0;
    __syncthreads();
    sm[t] += u;
    __syncthreads();
  }
  if (i < NN) tmp[i] = sm[t];
  if (t == SCAN_B - 1) blk_sums[blockIdx.x] = sm[t];
}

// ---------------- scan stage 3: row_ptr (block-offset recomputed locally) ----------------
__global__ __launch_bounds__(SCAN_B) void k_scan3(const int* __restrict__ tmp,
                                                  const int* __restrict__ blk_sums,
                                                  int* __restrict__ row_ptr) {
  __shared__ int sm[SCAN_B];
  int t = threadIdx.x;
  int v = (t < NSB) ? blk_sums[t] : 0;
  sm[t] = v;
  __syncthreads();
  for (int off = 1; off < SCAN_B; off <<= 1) {
    int u = (t >= off) ? sm[t - off] : 0;
    __syncthreads();
    sm[t] += u;
    __syncthreads();
  }
  int excl = sm[blockIdx.x] - blk_sums[blockIdx.x];
  int i = blockIdx.x * SCAN_B + t;
  if (i < NN) {
    row_ptr[i + 1] = tmp[i] + excl;
    if (i == 0) row_ptr[0] = 0;
  }
}

// ---------------- CSR fill: 2 edges/thread, atomic-free, u16 colv ----------------
__global__ void k_fill(const int* __restrict__ ei, const int* __restrict__ row_ptr,
                       const uint32_t* __restrict__ pos2, uint16_t* __restrict__ colv) {
  int e2 = blockIdx.x * blockDim.x + threadIdx.x;
  int e = e2 * 2;
  if (e < NE) {
    int2 s = *reinterpret_cast<const int2*>(&ei[e]);
    int2 d = *reinterpret_cast<const int2*>(&ei[NE + e]);
    uint32_t pp = pos2[e2];
    colv[row_ptr[d.x] + (int)(pp & 0xffffu)] = (uint16_t)s.x;
    colv[row_ptr[d.y] + (int)(pp >> 16)]     = (uint16_t)s.y;
  }
}

// ---------------- aggregate: XCD-affine chunked gather, batched ----------------
// block = 4 nodes x 1 chunk; chunk = (bid&7)>>1 (XCD round-robin).
// wave = node; lane = (eg=lane>>4, ch2=lane&15): 4 edge-slots x 16 lanes (64B line/edge).
// Loop: unmasked 16-edge batches (4 loads in flight/lane), then ONE masked 4-slot tail.
__global__ __launch_bounds__(256) void k_agg(const uint32_t* __restrict__ hc,
                                             const int* __restrict__ row_ptr,
                                             const uint16_t* __restrict__ colv,
                                             const float* __restrict__ dinv,
                                             const float* __restrict__ bias,
                                             float* __restrict__ z) {
  int bid = blockIdx.x;
  int wave = threadIdx.x >> 6;
  int lane = threadIdx.x & 63;
  int sub = bid & 7;
  int chunk = sub >> 1;
  int ng = (bid >> 3) * 2 + (sub & 1);     // 0..12499
  int node = ng * 4 + wave;                // < 50000
  int eg = lane >> 4;                      // edge slot 0..3
  int ch2 = lane & 15;                     // 2 channels: chunk*32 + ch2*2

  const uint32_t* hcc = hc + (size_t)chunk * NN * 16;
  float ax = 0.f, ay = 0.f;
  int e = row_ptr[node], end = row_ptr[node + 1];

  while (e + 16 <= end) {                  // unmasked 16-edge batches
    int s[4]; uint32_t m[4];
#pragma unroll
    for (int q = 0; q < 4; ++q) s[q] = colv[e + eg + 4 * q];
#pragma unroll
    for (int q = 0; q < 4; ++q) m[q] = hcc[(size_t)s[q] * 16 + ch2];
#pragma unroll
    for (int q = 0; q < 4; ++q) {
      ax += bf_lo(m[q]);
      ay += bf_hi(m[q]);
    }
    e += 16;
  }
  if (e < end) {                           // tail < 16 edges: one masked 4-slot batch
    int s[4]; uint32_t m[4]; bool ok[4];
#pragma unroll
    for (int q = 0; q < 4; ++q) {
      int ee = e + eg + 4 * q;
      ok[q] = ee < end;
      s[q] = colv[ok[q] ? ee : e];
    }
#pragma unroll
    for (int q = 0; q < 4; ++q) m[q] = hcc[(size_t)s[q] * 16 + ch2];
#pragma unroll
    for (int q = 0; q < 4; ++q) {
      uint32_t mm = ok[q] ? m[q] : 0u;
      ax += bf_lo(mm);
      ay += bf_hi(mm);
    }
  }
  ax += __shfl_xor(ax, 16); ay += __shfl_xor(ay, 16);
  ax += __shfl_xor(ax, 32); ay += __shfl_xor(ay, 32);
  if (lane < 16) {
    uint32_t ms = hcc[(size_t)node * 16 + ch2];    // self-loop (pre-scaled)
    ax += bf_lo(ms);
    ay += bf_hi(ms);
    float di = dinv[node];
    int col = chunk * 32 + ch2 * 2;
    float2 bb = *reinterpret_cast<const float2*>(&bias[col]);
    float zx = fmaxf(fmaf(ax, di, bb.x), 0.f);
    float zy = fmaxf(fmaf(ay, di, bb.y), 0.f);
    *reinterpret_cast<float2*>(&z[(size_t)node * DD + col]) = make_float2(zx, zy);
  }
}

// ---------------- BN stats stage 1: per-block partials, NO atomics ----------------
__global__ __launch_bounds__(256) void k_stats(const float* __restrict__ z,
                                               float* __restrict__ part) {
  int t = threadIdx.x;
  int c4 = t & 31;
  int rgrp = t >> 5;
  float sx = 0.f, sy = 0.f, sz = 0.f, sw = 0.f;
  float qx = 0.f, qy = 0.f, qz = 0.f, qw = 0.f;
  for (int r = blockIdx.x * 8 + rgrp; r < NN; r += NSTAT * 8) {
    float4 v = *reinterpret_cast<const float4*>(&z[(size_t)r * DD + c4 * 4]);
    sx += v.x; sy += v.y; sz += v.z; sw += v.w;
    qx = fmaf(v.x, v.x, qx); qy = fmaf(v.y, v.y, qy);
    qz = fmaf(v.z, v.z, qz); qw = fmaf(v.w, v.w, qw);
  }
  __shared__ float sm[2048], sm2[2048];
  sm[t * 4 + 0] = sx; sm[t * 4 + 1] = sy; sm[t * 4 + 2] = sz; sm[t * 4 + 3] = sw;
  sm2[t * 4 + 0] = qx; sm2[t * 4 + 1] = qy; sm2[t * 4 + 2] = qz; sm2[t * 4 + 3] = qw;
  __syncthreads();
  int c = t & 127;
  float acc = 0.f;
  if (t < 128) {
#pragma unroll
    for (int g = 0; g < 8; ++g) acc += sm[g * 128 + c];
  } else {
#pragma unroll
    for (int g = 0; g < 8; ++g) acc += sm2[g * 128 + c];
  }
  part[blockIdx.x * 256 + t] = acc;
}

// ---------------- BN stats stage 2: reduce partials (1 block) ----------------
__global__ __launch_bounds__(256) void k_stats2(const float* __restrict__ part,
                                                float* __restrict__ bn_sum,
                                                float* __restrict__ bn_sumsq) {
  int t = threadIdx.x;
  float acc = 0.f;
  for (int b = 0; b < NSTAT; ++b) acc += part[b * 256 + t];
  if (t < 128) bn_sum[t] = acc;
  else bn_sumsq[t - 128] = acc;
}

// ---------------- finalize: BN + dropout (float4 per thread, full grid) ----------------
__global__ __launch_bounds__(256) void k_final(float* __restrict__ z,
                                               const float* __restrict__ bn_sum,
                                               const float* __restrict__ bn_sumsq,
                                               const float* __restrict__ gamma,
                                               const float* __restrict__ beta) {
  int j4 = blockIdx.x * blockDim.x + threadIdx.x;
  if (j4 >= NN * DD / 4) return;
  int c4 = j4 & 31;
  const float invN = 1.0f / (float)NN;
  float4 s = *reinterpret_cast<const float4*>(&bn_sum[c4 * 4]);
  float4 q = *reinterpret_cast<const float4*>(&bn_sumsq[c4 * 4]);
  float4 g = *reinterpret_cast<const float4*>(&gamma[c4 * 4]);
  float4 bt = *reinterpret_cast<const float4*>(&beta[c4 * 4]);
  float4 v = *reinterpret_cast<const float4*>(&z[(size_t)j4 * 4]);
  float out[4];
  float mm[4] = {s.x * invN, s.y * invN, s.z * invN, s.w * invN};
  float qq[4] = {q.x * invN, q.y * invN, q.z * invN, q.w * invN};
  float gg[4] = {g.x, g.y, g.z, g.w};
  float bb[4] = {bt.x, bt.y, bt.z, bt.w};
  float vv[4] = {v.x, v.y, v.z, v.w};
#pragma unroll
  for (int i = 0; i < 4; ++i) {
    float var = qq[i] - mm[i] * mm[i];
    float rs = rsqrtf(var + 1e-5f);
    float val = (vv[i] - mm[i]) * rs * gg[i] + bb[i];
    uint32_t bits = threefry_bits((uint32_t)(j4 * 4 + i));
    float u = __uint_as_float((bits >> 9) | 0x3f800000u) - 1.0f;
    out[i] = (u < 0.9f) ? val * (1.0f / 0.9f) : 0.0f;
  }
  *reinterpret_cast<float4*>(&z[(size_t)j4 * 4]) = make_float4(out[0], out[1], out[2], out[3]);
}

// ---------------- launch ----------------
extern "C" void kernel_launch(void* const* d_in, const int* in_sizes, int n_in,
                              void* d_out, int out_size, void* d_ws, size_t ws_size,
                              hipStream_t stream) {
  const float* x     = (const float*)d_in[0];
  const int*   ei    = (const int*)d_in[1];
  const float* Wm    = (const float*)d_in[2];
  const float* bvec  = (const float*)d_in[3];
  const float* gamma = (const float*)d_in[4];
  const float* beta  = (const float*)d_in[5];
  float* zout = (float*)d_out;

  // workspace layout
  uint32_t* hc   = (uint32_t*)d_ws;                              // 4 chunks x NN x 64B (12.8MB)
  short8* wfh    = (short8*)((uint16_t*)d_ws + (size_t)NN * DD); // 32KB
  short8* wfl    = wfh + 2048;                                   // 32KB
  uint16_t* colv = (uint16_t*)(wfl + 2048);                      // NE u16
  uint32_t* pos2 = (uint32_t*)(colv + NE);                       // NE/2 u32
  int* cnt       = (int*)(pos2 + NE / 2);                        // NN (zeroed)
  float* bn_sum  = (float*)(cnt + NN);                           // DD
  float* bn_sumsq= bn_sum + DD;                                  // DD
  int* tmp_scan  = (int*)(bn_sumsq + DD);                        // NN
  int* row_ptr   = tmp_scan + NN;                                // NN+1
  float* dinv    = (float*)(row_ptr + NN + 1);                   // NN
  int* blk_sums  = (int*)(dinv + NN);                            // NSB
  float* part    = (float*)(blk_sums + NSB);                     // NSTAT*256

  hipMemsetAsync(cnt, 0, (size_t)NN * sizeof(int), stream);

  k_wpack<<<8, 256, 0, stream>>>(Wm, wfh, wfl);
  k_count<<<(NE / 2 + 255) / 256, 256, 0, stream>>>(ei, cnt, pos2);
  k_scan1<<<NSB, SCAN_B, 0, stream>>>(cnt, tmp_scan, blk_sums, dinv);
  k_scan3<<<NSB, SCAN_B, 0, stream>>>(tmp_scan, blk_sums, row_ptr);
  k_gemm<<<(NN + GBM - 1) / GBM, 256, 0, stream>>>(x, wfh, wfl, dinv, (uint2*)hc);
  k_fill<<<(NE / 2 + 255) / 256, 256, 0, stream>>>(ei, row_ptr, pos2, colv);
  k_agg<<<12500 * 4, 256, 0, stream>>>(hc, row_ptr, colv, dinv, bvec, zout);
  k_stats<<<NSTAT, 256, 0, stream>>>(zout, part);
  k_stats2<<<1, 256, 0, stream>>>(part, bn_sum, bn_sumsq);
  k_final<<<(NN * DD / 4 + 255) / 256, 256, 0, stream>>>(zout, bn_sum, bn_sumsq, gamma, beta);
}

// Round 15
// 160.499 us; speedup vs baseline: 1.3185x; 1.1155x over previous
//
#include <hip/hip_runtime.h>
#include <stdint.h>

// GNN block: GCNConv(x@W, sym-norm agg w/ self loops) -> ReLU -> BatchNorm(train) -> JAX dropout
// R15: revert to R12 (best measured, 160.5us x2). Chunked-k_agg investigation closed:
//      R13/R14 proved XCD-affine chunking cuts FETCH 84->27MB but the 4x edge-visit
//      instruction overhead (VALUBusy 57%) makes it slower (61us) than the full-row
//      gather (40us, issue-bound). k_agg floor established from both directions.

#define NN 50000
#define NE 800000
#define DD 128
#define SCAN_B 256
#define NSB ((NN + SCAN_B - 1) / SCAN_B)   // 196
#define NSTAT 400                          // k_stats blocks

using f32x4  = __attribute__((ext_vector_type(4))) float;
using short8 = __attribute__((ext_vector_type(8))) short;

// ---------------- threefry2x32 (JAX-compatible, partitionable path) ----------------
__device__ __forceinline__ uint32_t rotl32(uint32_t x, uint32_t d) {
  return (x << d) | (x >> (32u - d));
}

__device__ __forceinline__ uint32_t threefry_bits(uint32_t idx) {
  const uint32_t ks0 = 0u;
  const uint32_t ks1 = 42u;
  const uint32_t ks2 = 0x1BD11BDAu ^ ks0 ^ ks1;
  uint32_t x0 = ks0;
  uint32_t x1 = idx + ks1;
#define TF_R(r) { x0 += x1; x1 = rotl32(x1, (r)); x1 ^= x0; }
  TF_R(13u) TF_R(15u) TF_R(26u) TF_R(6u)
  x0 += ks1; x1 += ks2 + 1u;
  TF_R(17u) TF_R(29u) TF_R(16u) TF_R(24u)
  x0 += ks2; x1 += ks0 + 2u;
  TF_R(13u) TF_R(15u) TF_R(26u) TF_R(6u)
  x0 += ks0; x1 += ks1 + 3u;
  TF_R(17u) TF_R(29u) TF_R(16u) TF_R(24u)
  x0 += ks1; x1 += ks2 + 4u;
  TF_R(13u) TF_R(15u) TF_R(26u) TF_R(6u)
  x0 += ks2; x1 += ks0 + 5u;
#undef TF_R
  return x0 ^ x1;
}

__device__ __forceinline__ uint32_t f2bf(float f) {
  uint32_t u = __float_as_uint(f);
  return (u + 0x7fffu + ((u >> 16) & 1u)) >> 16;   // RNE
}
__device__ __forceinline__ float bf2f(uint32_t h) { return __uint_as_float(h << 16); }
__device__ __forceinline__ float bf_lo(uint32_t p) { return __uint_as_float(p << 16); }
__device__ __forceinline__ float bf_hi(uint32_t p) { return __uint_as_float(p & 0xffff0000u); }

// ---------------- W pre-pack into MFMA fragment order ----------------
__global__ __launch_bounds__(256) void k_wpack(const float* __restrict__ Wm,
                                               short8* __restrict__ wfh,
                                               short8* __restrict__ wfl) {
  int tid = blockIdx.x * 256 + threadIdx.x;   // 0..2047
  if (tid >= 32 * 64) return;
  int lane = tid & 63;
  int cfks = tid >> 6;        // ks = cfks>>3, cf = cfks&7
  int ks = cfks >> 3, cf = cfks & 7;
  int krow = ks * 32 + ((lane >> 4) << 3);
  int col = cf * 16 + (lane & 15);
  short8 h, l;
#pragma unroll
  for (int j = 0; j < 8; ++j) {
    float w = Wm[(size_t)(krow + j) * DD + col];
    uint32_t hb = f2bf(w);
    uint32_t lb = f2bf(w - bf2f(hb));
    h[j] = (short)hb;
    l[j] = (short)lb;
  }
  wfh[tid] = h;
  wfl[tid] = l;
}

// ---------------- MFMA GEMM: hbf[N][128](bf16) = (x @ W) * dinv[row], hi/lo compensated ----
#define GBM 128
__global__ __launch_bounds__(256) void k_gemm(const float* __restrict__ x,
                                              const short8* __restrict__ wfh,
                                              const short8* __restrict__ wfl,
                                              const float* __restrict__ dinv,
                                              uint16_t* __restrict__ hbf) {
  __shared__ uint4 ldsbuf[4096];              // 64 KiB: xhi @0, xlo @32768
  char* lds = (char*)ldsbuf;
  const int t = threadIdx.x;
  const int row0 = blockIdx.x * GBM;
  const int c4 = t & 31, rbase = t >> 5;

#pragma unroll
  for (int i = 0; i < 16; ++i) {
    int r = rbase + i * 8;
    int grow = row0 + r;
    float4 v = make_float4(0.f, 0.f, 0.f, 0.f);
    if (grow < NN)
      v = *reinterpret_cast<const float4*>(&x[(size_t)grow * DD + c4 * 4]);
    uint32_t h0 = f2bf(v.x), h1 = f2bf(v.y), h2 = f2bf(v.z), h3 = f2bf(v.w);
    uint32_t l0 = f2bf(v.x - bf2f(h0)), l1 = f2bf(v.y - bf2f(h1));
    uint32_t l2 = f2bf(v.z - bf2f(h2)), l3 = f2bf(v.w - bf2f(h3));
    int byte = (r * 256 + c4 * 8) ^ ((r & 7) << 4);
    *reinterpret_cast<uint2*>(lds + byte) = make_uint2(h0 | (h1 << 16), h2 | (h3 << 16));
    *reinterpret_cast<uint2*>(lds + 32768 + byte) = make_uint2(l0 | (l1 << 16), l2 | (l3 << 16));
  }
  __syncthreads();

  const int wv = t >> 6, l = t & 63;
  f32x4 acc[2][8] = {};
#pragma unroll
  for (int ks = 0; ks < 4; ++ks) {
    short8 ah[2], al[2];
#pragma unroll
    for (int rf = 0; rf < 2; ++rf) {
      int r = wv * 32 + rf * 16 + (l & 15);
      int byte = (r * 256 + ks * 64 + ((l >> 4) << 4)) ^ ((r & 7) << 4);
      ah[rf] = *reinterpret_cast<const short8*>(lds + byte);
      al[rf] = *reinterpret_cast<const short8*>(lds + 32768 + byte);
    }
#pragma unroll
    for (int cf = 0; cf < 8; ++cf) {
      short8 bh = wfh[(ks * 8 + cf) * 64 + l];
      short8 bl = wfl[(ks * 8 + cf) * 64 + l];
#pragma unroll
      for (int rf = 0; rf < 2; ++rf) {
        acc[rf][cf] = __builtin_amdgcn_mfma_f32_16x16x32_bf16(ah[rf], bl, acc[rf][cf], 0, 0, 0);
        acc[rf][cf] = __builtin_amdgcn_mfma_f32_16x16x32_bf16(al[rf], bh, acc[rf][cf], 0, 0, 0);
        acc[rf][cf] = __builtin_amdgcn_mfma_f32_16x16x32_bf16(ah[rf], bh, acc[rf][cf], 0, 0, 0);
      }
    }
  }
  __syncthreads();   // reuse LDS for output repack

#pragma unroll
  for (int rf = 0; rf < 2; ++rf)
#pragma unroll
    for (int i = 0; i < 4; ++i) {
      int row = wv * 32 + rf * 16 + ((l >> 4) << 2) + i;
      int grow = row0 + row;
      float dv = (grow < NN) ? dinv[grow] : 0.f;
#pragma unroll
      for (int cf = 0; cf < 8; ++cf) {
        int col = cf * 16 + (l & 15);
        int byte = (row * 256 + col * 2) ^ ((row & 7) << 4);
        *reinterpret_cast<uint16_t*>(lds + byte) = (uint16_t)f2bf(acc[rf][cf][i] * dv);
      }
    }
  __syncthreads();
#pragma unroll
  for (int i = 0; i < 16; ++i) {
    int r = rbase + i * 8;
    int grow = row0 + r;
    if (grow < NN) {
      int byte = (r * 256 + c4 * 8) ^ ((r & 7) << 4);
      uint2 v = *reinterpret_cast<const uint2*>(lds + byte);
      *reinterpret_cast<uint2*>(&hbf[(size_t)grow * DD + c4 * 4]) = v;
    }
  }
}

// ---------------- degree count + slot assignment: 2 edges/thread, packed u16 pos ----------------
__global__ void k_count(const int* __restrict__ ei, int* __restrict__ cnt,
                        uint32_t* __restrict__ pos2) {
  int e2 = blockIdx.x * blockDim.x + threadIdx.x;
  int e = e2 * 2;
  if (e < NE) {
    int2 d = *reinterpret_cast<const int2*>(&ei[NE + e]);
    uint32_t p0 = (uint32_t)atomicAdd(&cnt[d.x], 1) & 0xffffu;
    uint32_t p1 = (uint32_t)atomicAdd(&cnt[d.y], 1) & 0xffffu;
    pos2[e2] = p0 | (p1 << 16);
  }
}

// ---------------- scan stage 1: block-inclusive scan + dinv ----------------
__global__ __launch_bounds__(SCAN_B) void k_scan1(const int* __restrict__ cnt,
                                                  int* __restrict__ tmp,
                                                  int* __restrict__ blk_sums,
                                                  float* __restrict__ dinv) {
  __shared__ int sm[SCAN_B];
  int t = threadIdx.x;
  int i = blockIdx.x * SCAN_B + t;
  int v = (i < NN) ? cnt[i] : 0;
  if (i < NN) dinv[i] = rsqrtf((float)v + 1.0f);
  sm[t] = v;
  __syncthreads();
  for (int off = 1; off < SCAN_B; off <<= 1) {
    int u = (t >= off) ? sm[t - off] : 0;
    __syncthreads();
    sm[t] += u;
    __syncthreads();
  }
  if (i < NN) tmp[i] = sm[t];
  if (t == SCAN_B - 1) blk_sums[blockIdx.x] = sm[t];
}

// ---------------- scan stage 3: row_ptr (block-offset recomputed locally) ----------------
__global__ __launch_bounds__(SCAN_B) void k_scan3(const int* __restrict__ tmp,
                                                  const int* __restrict__ blk_sums,
                                                  int* __restrict__ row_ptr) {
  __shared__ int sm[SCAN_B];
  int t = threadIdx.x;
  int v = (t < NSB) ? blk_sums[t] : 0;
  sm[t] = v;
  __syncthreads();
  for (int off = 1; off < SCAN_B; off <<= 1) {
    int u = (t >= off) ? sm[t - off] : 0;
    __syncthreads();
    sm[t] += u;
    __syncthreads();
  }
  int excl = sm[blockIdx.x] - blk_sums[blockIdx.x];
  int i = blockIdx.x * SCAN_B + t;
  if (i < NN) {
    row_ptr[i + 1] = tmp[i] + excl;
    if (i == 0) row_ptr[0] = 0;
  }
}

// ---------------- CSR fill: 2 edges/thread, atomic-free, u16 colv ----------------
__global__ void k_fill(const int* __restrict__ ei, const int* __restrict__ row_ptr,
                       const uint32_t* __restrict__ pos2, uint16_t* __restrict__ colv) {
  int e2 = blockIdx.x * blockDim.x + threadIdx.x;
  int e = e2 * 2;
  if (e < NE) {
    int2 s = *reinterpret_cast<const int2*>(&ei[e]);
    int2 d = *reinterpret_cast<const int2*>(&ei[NE + e]);
    uint32_t pp = pos2[e2];
    colv[row_ptr[d.x] + (int)(pp & 0xffffu)] = (uint16_t)s.x;
    colv[row_ptr[d.y] + (int)(pp >> 16)]     = (uint16_t)s.y;
  }
}

// ---------------- aggregate: 16-batch -> 8-batch -> scalar tail (established floor) ----------------
__global__ __launch_bounds__(256) void k_agg(const uint16_t* __restrict__ hbf,
                                             const int* __restrict__ row_ptr,
                                             const uint16_t* __restrict__ colv,
                                             const float* __restrict__ dinv,
                                             const float* __restrict__ bias,
                                             float* __restrict__ z) {
  int wave = threadIdx.x >> 6;
  int lane = threadIdx.x & 63;
  int node = blockIdx.x * 4 + wave;
  if (node >= NN) return;
  const uint32_t* hp = reinterpret_cast<const uint32_t*>(hbf);

  uint32_t ms = hp[(size_t)node * 64 + lane];
  float ax = bf_lo(ms), ay = bf_hi(ms);

  int e = row_ptr[node], end = row_ptr[node + 1];
  while (e + 16 <= end) {
    int s[16]; uint32_t m[16];
#pragma unroll
    for (int q = 0; q < 16; ++q) s[q] = colv[e + q];
#pragma unroll
    for (int q = 0; q < 16; ++q) m[q] = hp[(size_t)s[q] * 64 + lane];
#pragma unroll
    for (int q = 0; q < 16; ++q) {
      ax += bf_lo(m[q]);
      ay += bf_hi(m[q]);
    }
    e += 16;
  }
  while (e + 8 <= end) {
    int s[8]; uint32_t m[8];
#pragma unroll
    for (int q = 0; q < 8; ++q) s[q] = colv[e + q];
#pragma unroll
    for (int q = 0; q < 8; ++q) m[q] = hp[(size_t)s[q] * 64 + lane];
#pragma unroll
    for (int q = 0; q < 8; ++q) {
      ax += bf_lo(m[q]);
      ay += bf_hi(m[q]);
    }
    e += 8;
  }
  while (e < end) {
    uint32_t m0 = hp[(size_t)colv[e] * 64 + lane];
    ax += bf_lo(m0);
    ay += bf_hi(m0);
    ++e;
  }
  float di = dinv[node];
  float2 bb = reinterpret_cast<const float2*>(bias)[lane];
  float zx = fmaxf(fmaf(ax, di, bb.x), 0.f);
  float zy = fmaxf(fmaf(ay, di, bb.y), 0.f);
  reinterpret_cast<float2*>(z)[(size_t)node * 64 + lane] = make_float2(zx, zy);
}

// ---------------- BN stats stage 1: per-block partials, NO atomics ----------------
__global__ __launch_bounds__(256) void k_stats(const float* __restrict__ z,
                                               float* __restrict__ part) {
  int t = threadIdx.x;
  int c4 = t & 31;
  int rgrp = t >> 5;
  float sx = 0.f, sy = 0.f, sz = 0.f, sw = 0.f;
  float qx = 0.f, qy = 0.f, qz = 0.f, qw = 0.f;
  for (int r = blockIdx.x * 8 + rgrp; r < NN; r += NSTAT * 8) {
    float4 v = *reinterpret_cast<const float4*>(&z[(size_t)r * DD + c4 * 4]);
    sx += v.x; sy += v.y; sz += v.z; sw += v.w;
    qx = fmaf(v.x, v.x, qx); qy = fmaf(v.y, v.y, qy);
    qz = fmaf(v.z, v.z, qz); qw = fmaf(v.w, v.w, qw);
  }
  __shared__ float sm[2048], sm2[2048];
  sm[t * 4 + 0] = sx; sm[t * 4 + 1] = sy; sm[t * 4 + 2] = sz; sm[t * 4 + 3] = sw;
  sm2[t * 4 + 0] = qx; sm2[t * 4 + 1] = qy; sm2[t * 4 + 2] = qz; sm2[t * 4 + 3] = qw;
  __syncthreads();
  int c = t & 127;
  float acc = 0.f;
  if (t < 128) {
#pragma unroll
    for (int g = 0; g < 8; ++g) acc += sm[g * 128 + c];
  } else {
#pragma unroll
    for (int g = 0; g < 8; ++g) acc += sm2[g * 128 + c];
  }
  part[blockIdx.x * 256 + t] = acc;
}

// ---------------- BN stats stage 2: reduce partials (1 block) ----------------
__global__ __launch_bounds__(256) void k_stats2(const float* __restrict__ part,
                                                float* __restrict__ bn_sum,
                                                float* __restrict__ bn_sumsq) {
  int t = threadIdx.x;
  float acc = 0.f;
  for (int b = 0; b < NSTAT; ++b) acc += part[b * 256 + t];
  if (t < 128) bn_sum[t] = acc;
  else bn_sumsq[t - 128] = acc;
}

// ---------------- finalize: BN + dropout (float4 per thread, full grid) ----------------
__global__ __launch_bounds__(256) void k_final(float* __restrict__ z,
                                               const float* __restrict__ bn_sum,
                                               const float* __restrict__ bn_sumsq,
                                               const float* __restrict__ gamma,
                                               const float* __restrict__ beta) {
  int j4 = blockIdx.x * blockDim.x + threadIdx.x;
  if (j4 >= NN * DD / 4) return;
  int c4 = j4 & 31;
  const float invN = 1.0f / (float)NN;
  float4 s = *reinterpret_cast<const float4*>(&bn_sum[c4 * 4]);
  float4 q = *reinterpret_cast<const float4*>(&bn_sumsq[c4 * 4]);
  float4 g = *reinterpret_cast<const float4*>(&gamma[c4 * 4]);
  float4 bt = *reinterpret_cast<const float4*>(&beta[c4 * 4]);
  float4 v = *reinterpret_cast<const float4*>(&z[(size_t)j4 * 4]);
  float out[4];
  float mm[4] = {s.x * invN, s.y * invN, s.z * invN, s.w * invN};
  float qq[4] = {q.x * invN, q.y * invN, q.z * invN, q.w * invN};
  float gg[4] = {g.x, g.y, g.z, g.w};
  float bb[4] = {bt.x, bt.y, bt.z, bt.w};
  float vv[4] = {v.x, v.y, v.z, v.w};
#pragma unroll
  for (int i = 0; i < 4; ++i) {
    float var = qq[i] - mm[i] * mm[i];
    float rs = rsqrtf(var + 1e-5f);
    float val = (vv[i] - mm[i]) * rs * gg[i] + bb[i];
    uint32_t bits = threefry_bits((uint32_t)(j4 * 4 + i));
    float u = __uint_as_float((bits >> 9) | 0x3f800000u) - 1.0f;
    out[i] = (u < 0.9f) ? val * (1.0f / 0.9f) : 0.0f;
  }
  *reinterpret_cast<float4*>(&z[(size_t)j4 * 4]) = make_float4(out[0], out[1], out[2], out[3]);
}

// ---------------- launch ----------------
extern "C" void kernel_launch(void* const* d_in, const int* in_sizes, int n_in,
                              void* d_out, int out_size, void* d_ws, size_t ws_size,
                              hipStream_t stream) {
  const float* x     = (const float*)d_in[0];
  const int*   ei    = (const int*)d_in[1];
  const float* Wm    = (const float*)d_in[2];
  const float* bvec  = (const float*)d_in[3];
  const float* gamma = (const float*)d_in[4];
  const float* beta  = (const float*)d_in[5];
  float* zout = (float*)d_out;

  // workspace layout
  uint16_t* hbf  = (uint16_t*)d_ws;                         // NN*DD bf16 (12.8MB)
  short8* wfh    = (short8*)(hbf + (size_t)NN * DD);        // 32KB
  short8* wfl    = wfh + 2048;                              // 32KB
  uint16_t* colv = (uint16_t*)(wfl + 2048);                 // NE u16
  uint32_t* pos2 = (uint32_t*)(colv + NE);                  // NE/2 u32 (packed u16 pairs)
  int* cnt       = (int*)(pos2 + NE / 2);                   // NN (zeroed)
  float* bn_sum  = (float*)(cnt + NN);                      // DD
  float* bn_sumsq= bn_sum + DD;                             // DD
  int* tmp_scan  = (int*)(bn_sumsq + DD);                   // NN
  int* row_ptr   = tmp_scan + NN;                           // NN+1
  float* dinv    = (float*)(row_ptr + NN + 1);              // NN
  int* blk_sums  = (int*)(dinv + NN);                       // NSB
  float* part    = (float*)(blk_sums + NSB);                // NSTAT*256

  hipMemsetAsync(cnt, 0, (size_t)NN * sizeof(int), stream);

  k_wpack<<<8, 256, 0, stream>>>(Wm, wfh, wfl);
  k_count<<<(NE / 2 + 255) / 256, 256, 0, stream>>>(ei, cnt, pos2);
  k_scan1<<<NSB, SCAN_B, 0, stream>>>(cnt, tmp_scan, blk_sums, dinv);
  k_scan3<<<NSB, SCAN_B, 0, stream>>>(tmp_scan, blk_sums, row_ptr);
  k_gemm<<<(NN + GBM - 1) / GBM, 256, 0, stream>>>(x, wfh, wfl, dinv, hbf);
  k_fill<<<(NE / 2 + 255) / 256, 256, 0, stream>>>(ei, row_ptr, pos2, colv);
  k_agg<<<(NN + 3) / 4, 256, 0, stream>>>(hbf, row_ptr, colv, dinv, bvec, zout);
  k_stats<<<NSTAT, 256, 0, stream>>>(zout, part);
  k_stats2<<<1, 256, 0, stream>>>(part, bn_sum, bn_sumsq);
  k_final<<<(NN * DD / 4 + 255) / 256, 256, 0, stream>>>(zout, bn_sum, bn_sumsq, gamma, beta);
}